// Round 9
// baseline (329.219 us; speedup 1.0000x reference)
//
#include <hip/hip_runtime.h>
#include <math.h>

#define EPSF 1e-5f

typedef short bf16x8 __attribute__((ext_vector_type(8)));
typedef float f32x4 __attribute__((ext_vector_type(4)));

static __device__ __forceinline__ unsigned short f2bf(float x) {
  unsigned u = __float_as_uint(x);
  unsigned r = (u + 0x7FFFu + ((u >> 16) & 1u)) >> 16;
  return (unsigned short)r;
}

union BU { uint4 u; bf16x8 v; };

// async global->LDS, 16B per lane; LDS dest = base + lane*16 (HW-linear),
// global source address is per-lane (carries gather + swizzle).
static __device__ __forceinline__ void gload16(const void* g, void* l) {
  __builtin_amdgcn_global_load_lds(
      (const __attribute__((address_space(1))) unsigned int*)g,
      (__attribute__((address_space(3))) unsigned int*)l, 16, 0, 0);
}

// ---------------- Prep (fused): cvt_x | bpack | hist ----------------
// Row space k=0..159 for B: k<32 -> W[128+k] (eattr); 32..95 -> W[0..63]
// (x_dst); 96..159 -> W[64..127] (x_src). lane l holds
// B[k=(l>>4)*8+i][col=(t8&3)*16+(l&15)], t8<4 => Wf else Ws.
__global__ __launch_bounds__(256) void prep_kernel(
    const float* __restrict__ x, const float* __restrict__ Wf,
    const float* __restrict__ Ws, const int* __restrict__ ei,
    unsigned short* __restrict__ xbf, unsigned short* __restrict__ Bfrag,
    int* __restrict__ deg, int NCV, int total8, int E) {
  const int b = blockIdx.x, t = threadIdx.x;
  if (b < NCV) {
    int i = b * 256 + t;
    if (i < total8) {
      float4 a = ((const float4*)x)[i * 2];
      float4 c = ((const float4*)x)[i * 2 + 1];
      unsigned short o[8];
      o[0] = f2bf(a.x); o[1] = f2bf(a.y); o[2] = f2bf(a.z); o[3] = f2bf(a.w);
      o[4] = f2bf(c.x); o[5] = f2bf(c.y); o[6] = f2bf(c.z); o[7] = f2bf(c.w);
      ((uint4*)xbf)[i] = *(uint4*)o;
    }
  } else if (b < NCV + 10) {
    int g2 = (b - NCV) * 256 + t;
    if (g2 < 2560) {
      const int ks = g2 >> 9, t8 = (g2 >> 6) & 7, l = g2 & 63;
      const int q = l & 15, g = l >> 4;
      const float* W = (t8 < 4) ? Wf : Ws;
      const int col = (t8 & 3) * 16 + q;
      unsigned short out[8];
#pragma unroll
      for (int i = 0; i < 8; ++i) {
        int r = ks * 32 + g * 8 + i;
        int wr = (r < 32) ? (128 + r) : (r - 32);
        out[i] = f2bf(W[(size_t)wr * 64 + col]);
      }
      *(uint4*)&Bfrag[((size_t)(ks * 8 + t8) * 64 + l) * 8] = *(uint4*)out;
    }
  } else {
    int i = (b - NCV - 10) * 256 + t;
    if (i < E) atomicAdd(&deg[ei[E + i]], 1);
  }
}

// ---------------- CSR build: 3-phase parallel exclusive scan ----------------
__global__ __launch_bounds__(256) void scan_a(const int* __restrict__ deg,
                                              int* __restrict__ bsum, int N) {
  const int idx = blockIdx.x * 256 + threadIdx.x;
  int v = (idx < N) ? deg[idx] : 0;
#pragma unroll
  for (int o = 32; o > 0; o >>= 1) v += __shfl_down(v, o);
  __shared__ int ws4[4];
  if ((threadIdx.x & 63) == 0) ws4[threadIdx.x >> 6] = v;
  __syncthreads();
  if (threadIdx.x == 0) bsum[blockIdx.x] = ws4[0] + ws4[1] + ws4[2] + ws4[3];
}

__global__ __launch_bounds__(256) void scan_b(const int* __restrict__ bsum,
                                              int* __restrict__ bpre, int NB) {
  const int t = threadIdx.x;
  const int lane = t & 63, w = t >> 6;
  int v = (t < NB) ? bsum[t] : 0;
  int sc = v;
#pragma unroll
  for (int o = 1; o < 64; o <<= 1) {
    int u = __shfl_up(sc, o);
    if (lane >= o) sc += u;
  }
  __shared__ int wsum[4];
  if (lane == 63) wsum[w] = sc;
  __syncthreads();
  int add = 0;
#pragma unroll
  for (int k = 0; k < 4; ++k) add += (k < w) ? wsum[k] : 0;
  bpre[t] = (sc - v) + add;
}

__global__ __launch_bounds__(256) void scan_c(const int* __restrict__ deg,
                                              const int* __restrict__ bpre,
                                              int* __restrict__ cursor, int N) {
  const int t = threadIdx.x;
  const int lane = t & 63, w = t >> 6;
  const int idx = blockIdx.x * 256 + t;
  int d = (idx < N) ? deg[idx] : 0;
  int sc = d;
#pragma unroll
  for (int o = 1; o < 64; o <<= 1) {
    int u = __shfl_up(sc, o);
    if (lane >= o) sc += u;
  }
  __shared__ int wsum[4];
  if (lane == 63) wsum[w] = sc;
  __syncthreads();
  int add = bpre[blockIdx.x];
#pragma unroll
  for (int k = 0; k < 4; ++k) add += (k < w) ? wsum[k] : 0;
  if (idx < N) cursor[idx] = add + (sc - d);
}

// ---------------- CSR build: scatter (src,dst) + eattr->bf16 sorted ----------
__global__ __launch_bounds__(256) void scatter_pack(
    const int* __restrict__ ei, int* __restrict__ cursor,
    const float* __restrict__ eattr, int2* __restrict__ epair2,
    unsigned short* __restrict__ eabf, int E) {
  int i = blockIdx.x * 256 + threadIdx.x;
  if (i >= E) return;
  const int dst = ei[E + i];
  const int pos = atomicAdd(&cursor[dst], 1);
  epair2[pos] = make_int2(ei[i], dst);
  const float4* er = (const float4*)(eattr + (size_t)i * 32);
  unsigned short o[32];
#pragma unroll
  for (int k = 0; k < 8; ++k) {
    float4 v = er[k];
    o[k * 4] = f2bf(v.x); o[k * 4 + 1] = f2bf(v.y);
    o[k * 4 + 2] = f2bf(v.z); o[k * 4 + 3] = f2bf(v.w);
  }
  uint4* dp = (uint4*)(eabf + (size_t)pos * 32);
#pragma unroll
  for (int k = 0; k < 4; ++k) dp[k] = ((uint4*)o)[k];
}

// ---------------- K2: persistent pipelined fused edge kernel -----------------
// Block handles a contiguous tile range (XCD-grouped). 2 LDS buffers of
// 5 slabs x [64][32]bf16 (source-swizzled chunk ^= (row>>1)&3). Staging is
// 5x global_load_lds per thread; raw s_barrier keeps next-tile loads in
// flight across the barrier. Epilogue: bias+sigmoid*softplus, run-compressed
// atomics into agg.
__global__ __launch_bounds__(256, 3) void edge_fused(
    const int2* __restrict__ epair2, const unsigned short* __restrict__ eabf,
    const unsigned short* __restrict__ xbf,
    const unsigned short* __restrict__ Bfrag, const float* __restrict__ bfv_,
    const float* __restrict__ bsv_, float* __restrict__ agg, int T, int N) {
  __shared__ __align__(16) unsigned char AshB[40960];
  __shared__ __align__(16) int metaLDS[128];

  const int tt = threadIdx.x, lane = tt & 63, w = tt >> 6;
  const int q = lane & 15, g = lane >> 4;

  // XCD-grouped contiguous tile range: same-XCD blocks share a dst range.
  const int nB = gridDim.x;  // 768
  const int c = (blockIdx.x & 7) * (nB >> 3) + (blockIdx.x >> 3);
  const int q8 = T / nB, r8 = T - q8 * nB;
  const int t0 = c * q8 + min(c, r8);
  const int t1 = t0 + q8 + (c < r8 ? 1 : 0);
  if (t0 >= t1) return;

  // B fragments + bias: block-lifetime registers
  bf16x8 Bf[5], Bs[5];
#pragma unroll
  for (int ks = 0; ks < 5; ++ks) {
    BU u1, u2;
    u1.u = ((const uint4*)Bfrag)[(ks * 8 + w) * 64 + lane];
    u2.u = ((const uint4*)Bfrag)[(ks * 8 + w + 4) * 64 + lane];
    Bf[ks] = u1.v; Bs[ks] = u2.v;
  }
  const int feat = w * 16 + q;
  const float bfv = bfv_[feat], bsv = bsv_[feat];

  int mSrc = 0, mDst = 0, nSrc = 0, nDst = 0;

  auto META = [&](int tile, int& S, int& D, int pbN) {
    int2 p = epair2[(size_t)tile * 64 + lane];
    S = p.x; D = p.y;
    int dp = __shfl_up(D, 1);
    int flag = (lane == 0 || D != dp) ? 1 : 0;
    int sc = flag;
#pragma unroll
    for (int o = 1; o < 64; o <<= 1) {
      int u = __shfl_up(sc, o);
      if (lane >= o) sc += u;
    }
    if (w == 0) metaLDS[pbN * 64 + lane] = ((sc - 1) << 20) | (D & 0xFFFFF);
  };

  auto STAGE = [&](int tile, int bufB, int S, int D) {
    const int row = (w << 4) + (lane >> 2);
    const int cx = (lane & 3) ^ ((row >> 1) & 3);   // source-side swizzle
    int dR = __shfl(D, row);
    int sR = __shfl(S, row);
    unsigned du = ((unsigned)dR < (unsigned)N) ? (unsigned)dR : 0u;
    unsigned su = ((unsigned)sR < (unsigned)N) ? (unsigned)sR : 0u;
    gload16(eabf + (size_t)tile * 2048 + row * 32 + cx * 8,
            AshB + bufB + w * 1024);
    gload16(xbf + (size_t)du * 64 + cx * 8, AshB + bufB + 4096 + w * 1024);
    gload16(xbf + (size_t)du * 64 + 32 + cx * 8,
            AshB + bufB + 4096 + (w + 4) * 1024);
    gload16(xbf + (size_t)su * 64 + cx * 8, AshB + bufB + 12288 + w * 1024);
    gload16(xbf + (size_t)su * 64 + 32 + cx * 8,
            AshB + bufB + 12288 + (w + 4) * 1024);
  };

  META(t0, mSrc, mDst, 0);
  STAGE(t0, 0, mSrc, mDst);
  int pb = 0;
  for (int t = t0; t < t1; ++t) {
    const int bufC = pb * 20480;
    if (t + 1 < t1) {
      // meta load's register dependency forces vmcnt(0) -> stage(t) landed;
      // stage(t+1)'s 5 gloads then stay in flight across the raw barrier.
      META(t + 1, nSrc, nDst, pb ^ 1);
      STAGE(t + 1, 20480 - bufC, nSrc, nDst);
    } else {
      asm volatile("s_waitcnt vmcnt(0)" ::: "memory");
    }
    asm volatile("s_waitcnt lgkmcnt(0)" ::: "memory");
    __builtin_amdgcn_sched_barrier(0);
    __builtin_amdgcn_s_barrier();
    __builtin_amdgcn_sched_barrier(0);

    f32x4 accf[4], accs[4];
#pragma unroll
    for (int mt = 0; mt < 4; ++mt) {
      accf[mt] = (f32x4){0.f, 0.f, 0.f, 0.f};
      accs[mt] = (f32x4){0.f, 0.f, 0.f, 0.f};
    }
#pragma unroll
    for (int ks = 0; ks < 5; ++ks) {
#pragma unroll
      for (int mt = 0; mt < 4; ++mt) {
        const int row = mt * 16 + q;
        const int ch = g ^ ((row >> 1) & 3);        // read-side swizzle
        const bf16x8 a =
            *(const bf16x8*)(AshB + bufC + ks * 4096 + row * 64 + ch * 16);
        accf[mt] = __builtin_amdgcn_mfma_f32_16x16x32_bf16(a, Bf[ks],
                                                           accf[mt], 0, 0, 0);
        accs[mt] = __builtin_amdgcn_mfma_f32_16x16x32_bf16(a, Bs[ks],
                                                           accs[mt], 0, 0, 0);
      }
    }

#pragma unroll
    for (int mt = 0; mt < 4; ++mt) {
      const int e0 = mt * 16 + g * 4;
      const uint4 mw = *(const uint4*)&metaLDS[pb * 64 + e0];
      float mm[4];
#pragma unroll
      for (int r = 0; r < 4; ++r) {
        float F = accf[mt][r] + bfv;
        float S = accs[mt][r] + bsv;
        float sig = __builtin_amdgcn_rcpf(1.0f + __expf(-F));
        float sp = fmaxf(S, 0.f) + __logf(1.0f + __expf(-fabsf(S)));
        mm[r] = sig * sp;
      }
      const unsigned u0 = mw.x, u1 = mw.y, u2 = mw.z, u3 = mw.w;
      const unsigned d0 = u0 & 0xFFFFFu, d1 = u1 & 0xFFFFFu,
                     d2 = u2 & 0xFFFFFu, d3 = u3 & 0xFFFFFu;
      const unsigned r0 = u0 >> 20, r1 = u1 >> 20, r2 = u2 >> 20, r3 = u3 >> 20;
      float a_ = mm[0];
      unsigned cur = r0, dc = d0;
      if (r1 == cur) a_ += mm[1];
      else {
        if (dc < (unsigned)N) atomicAdd(&agg[(size_t)dc * 64 + feat], a_);
        cur = r1; dc = d1; a_ = mm[1];
      }
      if (r2 == cur) a_ += mm[2];
      else {
        if (dc < (unsigned)N) atomicAdd(&agg[(size_t)dc * 64 + feat], a_);
        cur = r2; dc = d2; a_ = mm[2];
      }
      if (r3 == cur) a_ += mm[3];
      else {
        if (dc < (unsigned)N) atomicAdd(&agg[(size_t)dc * 64 + feat], a_);
        cur = r3; dc = d3; a_ = mm[3];
      }
      if (dc < (unsigned)N) atomicAdd(&agg[(size_t)dc * 64 + feat], a_);
    }

    mSrc = nSrc; mDst = nDst;
    pb ^= 1;
    __builtin_amdgcn_s_barrier();   // readers done before next overwrite
  }
}

// ---------------- K3: per-feature reductions over agg and x ----------------
__global__ __launch_bounds__(256) void stats_kernel(
    const float* __restrict__ agg, const float* __restrict__ x,
    float* __restrict__ stats, int N) {
  const int f = threadIdx.x & 63;
  const int sub = threadIdx.x >> 6;
  float sa = 0, sa2 = 0, sx = 0, sx2 = 0, sax = 0;
  for (int r = blockIdx.x * 4 + sub; r < N; r += gridDim.x * 4) {
    float a = agg[(size_t)r * 64 + f];
    float xv = x[(size_t)r * 64 + f];
    sa += a; sa2 += a * a; sx += xv; sx2 += xv * xv; sax += a * xv;
  }
  __shared__ float lds[4][5][64];
  lds[sub][0][f] = sa; lds[sub][1][f] = sa2; lds[sub][2][f] = sx;
  lds[sub][3][f] = sx2; lds[sub][4][f] = sax;
  __syncthreads();
  if (sub == 0) {
#pragma unroll
    for (int i = 0; i < 5; ++i) {
      float v = lds[0][i][f] + lds[1][i][f] + lds[2][i][f] + lds[3][i][f];
      atomicAdd(&stats[i * 64 + f], v);
    }
  }
}

// ---------------- K5: finalize + BN+res+LN+softplus + pooling ----------------
__global__ __launch_bounds__(256) void node_finish(
    const float* __restrict__ stats, const float* __restrict__ bn_w,
    const float* __restrict__ bn_b, const float* __restrict__ agg,
    const float* __restrict__ x, const int* __restrict__ batch,
    const float* __restrict__ ln_w, const float* __restrict__ ln_b,
    float* __restrict__ add_pool, float* __restrict__ counts, int N,
    int chunk) {
  const int f = threadIdx.x & 63;
  const int sub = threadIdx.x >> 6;
  const float Nf = (float)N;
  const float invN = 1.0f / Nf;
  float Sa = stats[f], Sa2 = stats[64 + f], Sx = stats[128 + f],
        Sx2 = stats[192 + f], Sax = stats[256 + f];
  float mu = Sa * invN;
  float var = Sa2 * invN - mu * mu;
  const float alpha = bn_w[f] / sqrtf(var + EPSF);
  const float beta = bn_b[f] - mu * alpha;
  float Sh = alpha * Sa + Nf * beta + Sx;
  float Sh2 = alpha * alpha * Sa2 + Sx2 + Nf * beta * beta +
              2.f * alpha * Sax + 2.f * alpha * beta * Sa + 2.f * beta * Sx;
#pragma unroll
  for (int o = 32; o > 0; o >>= 1) {
    Sh += __shfl_xor(Sh, o);
    Sh2 += __shfl_xor(Sh2, o);
  }
  const float cnt = Nf * 64.0f;
  const float mean = Sh / cnt;
  const float msq = Sh2 / cnt - mean * mean;
  const float rden = 1.0f / (sqrtf(fmaxf(msq, 0.f)) + EPSF);
  const float lw = ln_w[f] * rden;
  const float lb = ln_b[f];

  const int r0 = blockIdx.x * chunk;
  const int r1 = min(N, r0 + chunk);
  float acc = 0.f, cacc = 0.f;
  int curg = -1;
  for (int r = r0 + sub; r < r1; r += 4) {
    int g = batch[r];
    if (g != curg) {
      if (curg >= 0) {
        atomicAdd(&add_pool[(size_t)curg * 64 + f], acc);
        if (f == 0) atomicAdd(&counts[curg], cacc);
      }
      curg = g; acc = 0.f; cacc = 0.f;
    }
    float h = fmaf(alpha, agg[(size_t)r * 64 + f], beta) + x[(size_t)r * 64 + f];
    float v = (h - mean) * lw + lb;
    float sp = fmaxf(v, 0.f) + __logf(1.0f + __expf(-fabsf(v)));
    acc += sp; cacc += 1.f;
  }
  if (curg >= 0) {
    atomicAdd(&add_pool[(size_t)curg * 64 + f], acc);
    if (f == 0) atomicAdd(&counts[curg], cacc);
  }
}

// ---------------- K6: graph head (vectorized) ----------------
__global__ __launch_bounds__(1024) void graph_out(
    const float* __restrict__ add_pool, const float* __restrict__ counts,
    const float* __restrict__ Wl, const float* __restrict__ bl,
    const float* __restrict__ w4, const float* __restrict__ b4,
    float* __restrict__ out, int G) {
  const int t = threadIdx.x;
  const int g = t >> 1, c = t & 1;
  float cnt = fmaxf(counts[g], 1.0f);
  float inv = 1.0f / cnt;
  const float4* ap4 = (const float4*)(add_pool + (size_t)g * 64);
  const float4* W4 = (const float4*)Wl;
  float v = bl[c];
#pragma unroll 4
  for (int k4 = 0; k4 < 16; ++k4) {
    float4 a4 = ap4[k4];
    float4 wa = W4[k4 * 2];
    float4 wb = W4[k4 * 2 + 1];
    float4 wc = W4[32 + k4 * 2];
    float4 wd = W4[32 + k4 * 2 + 1];
    float m0 = c ? wa.y : wa.x, m1 = c ? wa.w : wa.z;
    float m2 = c ? wb.y : wb.x, m3 = c ? wb.w : wb.z;
    float a0 = c ? wc.y : wc.x, a1 = c ? wc.w : wc.z;
    float a2 = c ? wd.y : wd.x, a3 = c ? wd.w : wd.z;
    v = fmaf(a4.x, fmaf(m0, inv, a0), v);
    v = fmaf(a4.y, fmaf(m1, inv, a1), v);
    v = fmaf(a4.z, fmaf(m2, inv, a2), v);
    v = fmaf(a4.w, fmaf(m3, inv, a3), v);
  }

  __shared__ float red[16];
  __shared__ float bc[2];
  float sum = v;
#pragma unroll
  for (int o = 32; o > 0; o >>= 1) sum += __shfl_down(sum, o);
  if ((t & 63) == 0) red[t >> 6] = sum;
  __syncthreads();
  if (t == 0) {
    float tot = 0;
#pragma unroll
    for (int i = 0; i < 16; ++i) tot += red[i];
    bc[0] = tot * (1.0f / 1024.0f);
  }
  __syncthreads();
  const float mean = bc[0];
  const float xc = v - mean;
  float sq = xc * xc;
  __syncthreads();
#pragma unroll
  for (int o = 32; o > 0; o >>= 1) sq += __shfl_down(sq, o);
  if ((t & 63) == 0) red[t >> 6] = sq;
  __syncthreads();
  if (t == 0) {
    float tot = 0;
#pragma unroll
    for (int i = 0; i < 16; ++i) tot += red[i];
    bc[1] = 1.0f / (sqrtf(tot * (1.0f / 1024.0f)) + EPSF);
  }
  __syncthreads();
  out[t] = xc * bc[1] * w4[c] + b4[c];
}

extern "C" void kernel_launch(void* const* d_in, const int* in_sizes, int n_in,
                              void* d_out, int out_size, void* d_ws,
                              size_t ws_size, hipStream_t stream) {
  const float* x = (const float*)d_in[0];
  const int* ei = (const int*)d_in[1];
  const float* eattr = (const float*)d_in[2];
  const int* batch = (const int*)d_in[3];
  const float* Wf = (const float*)d_in[4];
  const float* bf = (const float*)d_in[5];
  const float* Ws = (const float*)d_in[6];
  const float* bs = (const float*)d_in[7];
  const float* bn_w = (const float*)d_in[8];
  const float* bn_b = (const float*)d_in[9];
  const float* ln_w = (const float*)d_in[10];
  const float* ln_b = (const float*)d_in[11];
  const float* Wl = (const float*)d_in[12];
  const float* bl = (const float*)d_in[13];
  const float* w4 = (const float*)d_in[14];
  const float* b4 = (const float*)d_in[15];

  const int N = in_sizes[0] / 64;
  const int E = in_sizes[2] / 32;
  const int G = 512;
  const int NB = (N + 255) / 256;
  const int T = (E + 63) / 64;
  const int NCV = (N * 8 + 255) / 256;  // cvt_x blocks (N*64/8 items)
  const int NH = (E + 255) / 256;

  // Workspace layout (elements; each chunk multiple of 4 => 16B alignment).
  // Zero region contiguous: [agg | stats | add_pool | counts | deg]
  float* ws = (float*)d_ws;
  float* agg = ws;                                   // N*64  [zeroed]
  float* stats = agg + (size_t)N * 64;               // 320   [zeroed]
  float* add_pool = stats + 320;                     // G*64  [zeroed]
  float* counts = add_pool + (size_t)G * 64;         // G     [zeroed]
  int* deg = (int*)(counts + G);                     // N     [zeroed]
  int* cursor = deg + N;                             // N
  int* bsum = cursor + N;                            // 256
  int* bpre = bsum + 256;                            // 256
  unsigned short* Bfrag = (unsigned short*)(bpre + 256);   // 20480 ush
  unsigned short* xbf = Bfrag + 20480;                     // N*64 ush
  unsigned short* eabf = xbf + (size_t)N * 64;             // T*2048 ush
  int2* epair2 = (int2*)(eabf + (size_t)T * 2048);         // T*64 int2

  size_t zeroFloats = (size_t)N * 64 + 320 + (size_t)G * 64 + G + N;
  hipMemsetAsync(agg, 0, zeroFloats * sizeof(float), stream);
  const int padE = T * 64 - E;
  if (padE > 0) hipMemsetAsync(epair2 + E, 0xFF, (size_t)padE * 8, stream);

  prep_kernel<<<NCV + 10 + NH, 256, 0, stream>>>(x, Wf, Ws, ei, xbf, Bfrag,
                                                 deg, NCV, N * 8, E);
  scan_a<<<NB, 256, 0, stream>>>(deg, bsum, N);
  scan_b<<<1, 256, 0, stream>>>(bsum, bpre, NB);
  scan_c<<<NB, 256, 0, stream>>>(deg, bpre, cursor, N);
  scatter_pack<<<NH, 256, 0, stream>>>(ei, cursor, eattr, epair2, eabf, E);
  edge_fused<<<768, 256, 0, stream>>>(epair2, eabf, xbf, Bfrag, bf, bs, agg, T,
                                      N);
  stats_kernel<<<512, 256, 0, stream>>>(agg, x, stats, N);
  const int chunk = (N + 511) / 512;
  node_finish<<<512, 256, 0, stream>>>(stats, bn_w, bn_b, agg, x, batch, ln_w,
                                       ln_b, add_pool, counts, N, chunk);
  graph_out<<<1, 1024, 0, stream>>>(add_pool, counts, Wl, bl, w4, b4,
                                    (float*)d_out, G);
}